// Round 3
// baseline (1807.286 us; speedup 1.0000x reference)
//
#include <hip/hip_runtime.h>
#include <hip/hip_bf16.h>
#include <float.h>

// Problem constants
#define N_ROWS 32768   // B*L
#define E_DIM  256
#define K_CODES 8192

// d_out: FLOAT32, 16809985 elements: z_q_st[8388608] idx[32768] loss[1] res[8388608]
// ws layout (bytes):
//   S_z      f32[32768]  @ 0
//   S_c      f32[8192]   @ 131072
//   idx      i32[32768]  @ 163840
//   partials f64[2048]   @ 294912

__device__ __forceinline__ float sqf(float x) { return __fmul_rn(x, x); }

// ---------------------------------------------------------------------------
// Kernel 1: row sum-of-squares, bit-exact emulation of numpy pairwise_sum
// (n=256 -> two 128 halves; each half: 8 strided accumulators, fixed tree).
// 32 rows/block. Blocks [0,1024): z rows; [1024,1280): codebook rows.
// ---------------------------------------------------------------------------
__global__ __launch_bounds__(256) void k_norms(const float* __restrict__ z,
                                               const float* __restrict__ cb,
                                               float* __restrict__ S_z,
                                               float* __restrict__ S_c) {
    __shared__ float tile[32][257];   // +1 pad
    int b = blockIdx.x;
    const float* src; float* dst; int row0;
    if (b < 1024) { src = z;  dst = S_z; row0 = b * 32; }
    else          { src = cb; dst = S_c; row0 = (b - 1024) * 32; }
    int t = threadIdx.x;
    for (int i = 0; i < 8; ++i) {
        int f  = i * 256 + t;     // float4 index, 2048 total
        int r  = f >> 6;          // [0,32)
        int c4 = f & 63;
        const float4 v = *reinterpret_cast<const float4*>(
            src + (size_t)(row0 + r) * E_DIM + c4 * 4);
        tile[r][c4 * 4 + 0] = v.x;
        tile[r][c4 * 4 + 1] = v.y;
        tile[r][c4 * 4 + 2] = v.z;
        tile[r][c4 * 4 + 3] = v.w;
    }
    __syncthreads();
    if (t < 32) {
        const float* a = tile[t];
        float halves[2];
        for (int h = 0; h < 2; ++h) {
            const float* p = a + h * 128;
            float r8[8];
            #pragma unroll
            for (int j = 0; j < 8; ++j) r8[j] = sqf(p[j]);
            for (int i = 8; i < 128; i += 8) {
                #pragma unroll
                for (int j = 0; j < 8; ++j) r8[j] = __fadd_rn(r8[j], sqf(p[i + j]));
            }
            halves[h] = __fadd_rn(
                __fadd_rn(__fadd_rn(r8[0], r8[1]), __fadd_rn(r8[2], r8[3])),
                __fadd_rn(__fadd_rn(r8[4], r8[5]), __fadd_rn(r8[6], r8[7])));
        }
        dst[row0 + t] = __fadd_rn(halves[0], halves[1]);
    }
}

// ---------------------------------------------------------------------------
// Kernel 2: fused fp32 GEMM + argmin.  1024 blocks x 256 threads.
// BM=32 rows: Zs fully K-resident, k-major [256][32] = 32 KB.
// BN=512 codes per n-iter, K-tiles of 8: Cs [8][512] = 16 KB. Total 48 KB.
// Thread tile 8 rows x 8 codes; codes split lo/hi: lane tx owns codes
// {tx*4+c} and {256+tx*4+c} -> each b-read is ds_read_b128 with granule==lane
// -> conflict-free. a-reads are wave-uniform (ty = t>>6 = wave id) ->
// LDS broadcast. dot chain: one accumulator per (row,code), k ascending
// 0..255, fmaf — emulates OpenBLAS sgemm accumulation bit-exactly.
// d = fl( fl(S_z+S_c) - 2*dot ) (2*acc exact); first-occurrence argmin.
// ---------------------------------------------------------------------------
__global__ __launch_bounds__(256) void k_argmin(const float* __restrict__ z,
                                                const float* __restrict__ cb,
                                                const float* __restrict__ S_z,
                                                const float* __restrict__ S_c,
                                                int* __restrict__ idx_out,
                                                float* __restrict__ idx_f32) {
    __shared__ float Zs[256 * 32];   // 32 KB: [k][row]
    __shared__ float Cs[8 * 512];    // 16 KB: [k_local][code]

    const int t    = threadIdx.x;
    const int tx   = t & 63;   // code lane
    const int ty   = t >> 6;   // wave id = row group
    const int row0 = blockIdx.x * 32;

    // ---- stage Zs once: 32 rows x 256 k, transposed into k-major ----
    for (int i = 0; i < 8; ++i) {
        int f  = i * 256 + t;     // 2048 float4
        int r  = f >> 6;          // [0,32)
        int kq = f & 63;
        const float4 v = *reinterpret_cast<const float4*>(
            z + (size_t)(row0 + r) * E_DIM + kq * 4);
        int k = kq * 4;
        Zs[(k + 0) * 32 + r] = v.x;
        Zs[(k + 1) * 32 + r] = v.y;
        Zs[(k + 2) * 32 + r] = v.z;
        Zs[(k + 3) * 32 + r] = v.w;
    }

    float Szr[8];
    #pragma unroll
    for (int r = 0; r < 8; ++r) Szr[r] = S_z[row0 + ty * 8 + r];

    float dmin[8]; int imin[8];
    #pragma unroll
    for (int r = 0; r < 8; ++r) { dmin[r] = FLT_MAX; imin[r] = 0; }

    for (int n = 0; n < 16; ++n) {          // 16 * 512 = 8192 codes
        float acc[8][8];                    // [row][code]: c 0..3 lo, 4..7 hi
        #pragma unroll
        for (int r = 0; r < 8; ++r)
            #pragma unroll
            for (int c = 0; c < 8; ++c) acc[r][c] = 0.0f;

        for (int kt = 0; kt < 32; ++kt) {   // 32 * 8 = 256 k
            __syncthreads();
            // stage Cs: 512 codes x 8 k (k-local), transposed
            for (int i = 0; i < 4; ++i) {
                int f  = i * 256 + t;        // 1024 float4
                int c  = f >> 1;             // [0,512)
                int kq = f & 1;
                const float4 v = *reinterpret_cast<const float4*>(
                    cb + (size_t)(n * 512 + c) * E_DIM + kt * 8 + kq * 4);
                int kl = kq * 4;
                Cs[(kl + 0) * 512 + c] = v.x;
                Cs[(kl + 1) * 512 + c] = v.y;
                Cs[(kl + 2) * 512 + c] = v.z;
                Cs[(kl + 3) * 512 + c] = v.w;
            }
            __syncthreads();
            #pragma unroll
            for (int kk = 0; kk < 8; ++kk) {
                const int kg = kt * 8 + kk;
                const float4 a0 = *reinterpret_cast<const float4*>(&Zs[kg * 32 + ty * 8]);
                const float4 a1 = *reinterpret_cast<const float4*>(&Zs[kg * 32 + ty * 8 + 4]);
                const float4 bl = *reinterpret_cast<const float4*>(&Cs[kk * 512 + tx * 4]);
                const float4 bh = *reinterpret_cast<const float4*>(&Cs[kk * 512 + 256 + tx * 4]);
                const float ar[8] = {a0.x, a0.y, a0.z, a0.w, a1.x, a1.y, a1.z, a1.w};
                const float br[8] = {bl.x, bl.y, bl.z, bl.w, bh.x, bh.y, bh.z, bh.w};
                #pragma unroll
                for (int r = 0; r < 8; ++r)
                    #pragma unroll
                    for (int c = 0; c < 8; ++c)
                        acc[r][c] = __builtin_fmaf(ar[r], br[c], acc[r][c]);
            }
        }
        // epilogue: d = fl(fl(Sz+Sc) - 2*acc); ascending j (lo then hi)
        #pragma unroll
        for (int c = 0; c < 8; ++c) {
            int j = n * 512 + ((c < 4) ? (tx * 4 + c) : (256 + tx * 4 + (c - 4)));
            float scj = S_c[j];
            #pragma unroll
            for (int r = 0; r < 8; ++r) {
                float tt = __fadd_rn(Szr[r], scj);
                float d  = __builtin_fmaf(-2.0f, acc[r][c], tt);
                if (d < dmin[r]) { dmin[r] = d; imin[r] = j; }
            }
        }
    }

    // ---- cross-thread reduction per row (lexicographic (d, idx)) ----
    __syncthreads();
    float* rd = Cs;                              // 2048 floats
    int*   ri = reinterpret_cast<int*>(Cs) + 2048;
    #pragma unroll
    for (int r = 0; r < 8; ++r) {
        rd[(ty * 8 + r) * 64 + tx] = dmin[r];
        ri[(ty * 8 + r) * 64 + tx] = imin[r];
    }
    __syncthreads();
    if (t < 32) {
        float best = rd[t * 64]; int bi = ri[t * 64];
        for (int q = 1; q < 64; ++q) {
            float d  = rd[t * 64 + q];
            int   i2 = ri[t * 64 + q];
            if (d < best || (d == best && i2 < bi)) { best = d; bi = i2; }
        }
        idx_out[row0 + t] = bi;
        idx_f32[row0 + t] = (float)bi;
    }
}

// ---------------------------------------------------------------------------
// Kernel 3: gather + straight-through outputs + loss partials. FLOAT out.
// Emulates: tmp = fl(zq - z); zqst = fl(z + tmp); res = fl(z - zqst).
// ---------------------------------------------------------------------------
__global__ __launch_bounds__(256) void k_outputs(const float* __restrict__ z,
                                                 const float* __restrict__ cb,
                                                 const int* __restrict__ idx,
                                                 float* __restrict__ out_zq,
                                                 float* __restrict__ out_res,
                                                 double* __restrict__ partials) {
    int b = blockIdx.x;
    int t = threadIdx.x;
    double acc = 0.0;
    for (int rr = 0; rr < 16; ++rr) {
        int row = b * 16 + rr;
        int id  = idx[row];
        int ids = id & (K_CODES - 1);           // fault guard only
        float zq = cb[(size_t)ids * E_DIM + t];
        float zv = z[(size_t)row * E_DIM + t];
        float tmp  = __fsub_rn(zq, zv);
        float zqst = __fadd_rn(zv, tmp);
        float res  = __fsub_rn(zv, zqst);
        out_zq[(size_t)row * E_DIM + t]  = zqst;
        out_res[(size_t)row * E_DIM + t] = res;
        acc += (double)__fmul_rn(tmp, tmp);
    }
    __shared__ double sd[256];
    sd[t] = acc;
    __syncthreads();
    for (int s = 128; s > 0; s >>= 1) {
        if (t < s) sd[t] += sd[t + s];
        __syncthreads();
    }
    if (t == 0) partials[b] = sd[0];
}

// ---------------------------------------------------------------------------
// Kernel 4: deterministic loss finalize. loss = m + 1.0*m (forward value).
// ---------------------------------------------------------------------------
__global__ __launch_bounds__(256) void k_loss(const double* __restrict__ partials,
                                              float* __restrict__ out_loss) {
    __shared__ double sd[256];
    int t = threadIdx.x;
    double a = 0.0;
    for (int i = 0; i < 8; ++i) a += partials[t * 8 + i];
    sd[t] = a;
    __syncthreads();
    for (int s = 128; s > 0; s >>= 1) {
        if (t < s) sd[t] += sd[t + s];
        __syncthreads();
    }
    if (t == 0) {
        float m = (float)(sd[0] / 8388608.0);
        out_loss[0] = __fadd_rn(m, __fmul_rn(1.0f, m));
    }
}

extern "C" void kernel_launch(void* const* d_in, const int* in_sizes, int n_in,
                              void* d_out, int out_size, void* d_ws, size_t ws_size,
                              hipStream_t stream) {
    const float* z  = (const float*)d_in[0];
    const float* cb = (const float*)d_in[1];
    float* out = (float*)d_out;                 // f32 output buffer

    char* ws = (char*)d_ws;
    float*  S_z      = (float*)(ws);
    float*  S_c      = (float*)(ws + 131072);
    int*    idx      = (int*)  (ws + 163840);
    double* partials = (double*)(ws + 294912);

    float* out_zq   = out;                 // 8388608 elements
    float* out_idx  = out + 8388608;       // 32768
    float* out_loss = out + 8421376;       // 1
    float* out_res  = out + 8421377;       // 8388608

    k_norms  <<<1280, 256, 0, stream>>>(z, cb, S_z, S_c);
    k_argmin <<<1024, 256, 0, stream>>>(z, cb, S_z, S_c, idx, out_idx);
    k_outputs<<<2048, 256, 0, stream>>>(z, cb, idx, out_zq, out_res, partials);
    k_loss   <<<1,    256, 0, stream>>>(partials, out_loss);
}

// Round 4
// 987.248 us; speedup vs baseline: 1.8306x; 1.8306x over previous
//
#include <hip/hip_runtime.h>
#include <hip/hip_bf16.h>
#include <float.h>

// Problem constants
#define N_ROWS 32768   // B*L
#define E_DIM  256
#define K_CODES 8192

// d_out: FLOAT32, 16809985 elements: z_q_st[8388608] idx[32768] loss[1] res[8388608]
// ws layout (bytes):
//   S_z      f32[32768]   @ 0
//   S_c      f32[8192]    @ 131072
//   idx      i32[32768]   @ 163840
//   partials f64[2048]    @ 294912
//   c_packed u16[2097152] @ 327680   (4,194,304 B)  -> total 4,521,984
#define WS_NEED 4521984

typedef _Float16 f16x8 __attribute__((ext_vector_type(8)));
typedef float    f32x4 __attribute__((ext_vector_type(4)));

__device__ __forceinline__ float sqf(float x) { return __fmul_rn(x, x); }

// ---------------------------------------------------------------------------
// Kernel 1: row sum-of-squares, bit-exact numpy pairwise_sum emulation.
// ---------------------------------------------------------------------------
__global__ __launch_bounds__(256) void k_norms(const float* __restrict__ z,
                                               const float* __restrict__ cb,
                                               float* __restrict__ S_z,
                                               float* __restrict__ S_c) {
    __shared__ float tile[32][257];
    int b = blockIdx.x;
    const float* src; float* dst; int row0;
    if (b < 1024) { src = z;  dst = S_z; row0 = b * 32; }
    else          { src = cb; dst = S_c; row0 = (b - 1024) * 32; }
    int t = threadIdx.x;
    for (int i = 0; i < 8; ++i) {
        int f  = i * 256 + t;
        int r  = f >> 6;
        int c4 = f & 63;
        const float4 v = *reinterpret_cast<const float4*>(
            src + (size_t)(row0 + r) * E_DIM + c4 * 4);
        tile[r][c4 * 4 + 0] = v.x;
        tile[r][c4 * 4 + 1] = v.y;
        tile[r][c4 * 4 + 2] = v.z;
        tile[r][c4 * 4 + 3] = v.w;
    }
    __syncthreads();
    if (t < 32) {
        const float* a = tile[t];
        float halves[2];
        for (int h = 0; h < 2; ++h) {
            const float* p = a + h * 128;
            float r8[8];
            #pragma unroll
            for (int j = 0; j < 8; ++j) r8[j] = sqf(p[j]);
            for (int i = 8; i < 128; i += 8) {
                #pragma unroll
                for (int j = 0; j < 8; ++j) r8[j] = __fadd_rn(r8[j], sqf(p[i + j]));
            }
            halves[h] = __fadd_rn(
                __fadd_rn(__fadd_rn(r8[0], r8[1]), __fadd_rn(r8[2], r8[3])),
                __fadd_rn(__fadd_rn(r8[4], r8[5]), __fadd_rn(r8[6], r8[7])));
        }
        dst[row0 + t] = __fadd_rn(halves[0], halves[1]);
    }
}

// ---------------------------------------------------------------------------
// Kernel 1b: split codebook into fp16 (scaled by 2^14), packed+pre-swizzled
// for linear global_load_lds staging. Layout: tile(=code>>8, 128KB each) ->
// kchunk(=k>>5, 16KB each) -> byte (col*64 + khi*16 + j*2) ^ ((col>>1)&3)<<4.
// ---------------------------------------------------------------------------
__global__ __launch_bounds__(256) void k_split(const float* __restrict__ cb,
                                               unsigned short* __restrict__ cp) {
    int e0 = (blockIdx.x * 256 + threadIdx.x) * 16;   // 512 blocks
    int code = e0 >> 8; int k0 = e0 & 255;
    int tile = code >> 8; int col = code & 255;
    size_t tb = (size_t)tile * 131072;
    for (int i = 0; i < 4; ++i) {
        const float4 v = *reinterpret_cast<const float4*>(
            cb + (size_t)code * E_DIM + k0 + i * 4);
        float vv[4] = {v.x, v.y, v.z, v.w};
        #pragma unroll
        for (int q = 0; q < 4; ++q) {
            int k = k0 + i * 4 + q;
            _Float16 h = (_Float16)(__fmul_rn(vv[q], 16384.0f));
            int kc = k >> 5, kin = k & 31, khi = kin >> 3, j = kin & 7;
            int byte = (col * 64 + khi * 16 + j * 2) ^ (((col >> 1) & 3) << 4);
            *reinterpret_cast<unsigned short*>((char*)cp + tb + (size_t)kc * 16384 + byte)
                = __builtin_bit_cast(unsigned short, h);
        }
    }
}

// ---------------------------------------------------------------------------
// exact recheck chain: reference-order serial fp32 FMA dot, k ascending.
// ---------------------------------------------------------------------------
__device__ __forceinline__ void chain_check(unsigned int pk, int row0,
                                            const float* __restrict__ z,
                                            const float* __restrict__ cb,
                                            const float* __restrict__ S_z,
                                            const float* __restrict__ S_c,
                                            unsigned long long* best) {
    int r = pk >> 13;
    int c = pk & 8191;
    const float* zp = z + (size_t)(row0 + r) * E_DIM;
    const float* cp = cb + (size_t)c * E_DIM;
    float acc = 0.0f;
    #pragma unroll 8
    for (int k4 = 0; k4 < 64; ++k4) {
        const float4 a = *reinterpret_cast<const float4*>(zp + k4 * 4);
        const float4 b = *reinterpret_cast<const float4*>(cp + k4 * 4);
        acc = __builtin_fmaf(a.x, b.x, acc);
        acc = __builtin_fmaf(a.y, b.y, acc);
        acc = __builtin_fmaf(a.z, b.z, acc);
        acc = __builtin_fmaf(a.w, b.w, acc);
    }
    float T = __fadd_rn(S_z[row0 + r], S_c[c]);
    float d = __builtin_fmaf(-2.0f, acc, T);
    unsigned long long key = ((unsigned long long)__float_as_uint(d) << 32)
                             | (unsigned int)c;
    atomicMin(best, key);
}

// ---------------------------------------------------------------------------
// Kernel 2 (fast): fp16 MFMA prefilter + exact recheck argmin.
// 512 blocks x 256 thr (4 waves). BM=64 rows (A fp16 in LDS, swizzled),
// BN=256 codes/iter from c_packed via double-buffered global_load_lds.
// Per wave: 64x64 output = 4x4 frags of mfma_f32_16x16x32_f16.
// ---------------------------------------------------------------------------
__global__ __launch_bounds__(256) void k_prefilter(const float* __restrict__ z,
                                                   const float* __restrict__ cb,
                                                   const unsigned short* __restrict__ cp,
                                                   const float* __restrict__ S_z,
                                                   const float* __restrict__ S_c,
                                                   int* __restrict__ idx_out,
                                                   float* __restrict__ idx_f32) {
    __shared__ __align__(16) unsigned short Alds[16384];      // 32 KB
    __shared__ __align__(16) unsigned short Blds[2][8192];    // 2 x 16 KB
    __shared__ unsigned int  queue[4][256];
    __shared__ unsigned long long best[64];
    __shared__ int qn[4];

    const int t   = threadIdx.x;
    const int w   = t >> 6;
    const int l   = t & 63;
    const int l15 = l & 15;
    const int lg  = l >> 4;
    const int row0 = blockIdx.x * 64;
    const float W = 3.0e-4f;

    if (t < 64) best[t] = ~0ull;
    if (t < 4)  qn[t] = 0;

    // ---- stage A: 64 rows x 256 k, fp32 -> fp16, swizzled ds writes ----
    {
        int r = t & 63, kq = t >> 6;          // k range [kq*64, kq*64+64)
        for (int i = 0; i < 16; ++i) {
            int k = kq * 64 + i * 4;
            const float4 v = *reinterpret_cast<const float4*>(
                z + (size_t)(row0 + r) * E_DIM + k);
            unsigned short h0 = __builtin_bit_cast(unsigned short, (_Float16)v.x);
            unsigned short h1 = __builtin_bit_cast(unsigned short, (_Float16)v.y);
            unsigned short h2 = __builtin_bit_cast(unsigned short, (_Float16)v.z);
            unsigned short h3 = __builtin_bit_cast(unsigned short, (_Float16)v.w);
            int byte = (r * 512 + k * 2) ^ ((r & 7) << 4);
            *reinterpret_cast<unsigned int*>((char*)Alds + byte)
                = (unsigned int)h0 | ((unsigned int)h1 << 16);
            *reinterpret_cast<unsigned int*>((char*)Alds + byte + 4)
                = (unsigned int)h2 | ((unsigned int)h3 << 16);
        }
    }

    // ---- prologue: stage chunk 0 into buf 0 ----
    {
        const char* src = (const char*)cp + w * 1024 + l * 16;
        char* db = (char*)Blds[0] + w * 1024;
        #pragma unroll
        for (int i = 0; i < 4; ++i)
            __builtin_amdgcn_global_load_lds(
                (const __attribute__((address_space(1))) unsigned int*)(src + i * 4096),
                (__attribute__((address_space(3))) unsigned int*)(db + i * 4096),
                16, 0, 0);
    }

    float Szr[16];
    #pragma unroll
    for (int rt = 0; rt < 4; ++rt)
        #pragma unroll
        for (int rg = 0; rg < 4; ++rg)
            Szr[rt * 4 + rg] = S_z[row0 + rt * 16 + lg * 4 + rg];

    float dmin[16], thr[16];
    #pragma unroll
    for (int e = 0; e < 16; ++e) { dmin[e] = FLT_MAX; thr[e] = -FLT_MAX; }

    __syncthreads();

    f32x4 acc[4][4];
    int buf = 0;
    for (int ci = 0; ci < 272; ++ci) {          // (32+2 revisit) iters * 8 chunks
        const int kc = ci & 7;
        const int it = ci >> 3;
        const int n  = (it < 32) ? it : (it - 32);

        if (kc == 0) {
            #pragma unroll
            for (int rt = 0; rt < 4; ++rt)
                #pragma unroll
                for (int ct = 0; ct < 4; ++ct)
                    acc[rt][ct] = (f32x4){0.f, 0.f, 0.f, 0.f};
        }

        // stage next chunk into buf^1
        if (ci + 1 < 272) {
            int cj = ci + 1;
            int kc2 = cj & 7, it2 = cj >> 3;
            int n2 = (it2 < 32) ? it2 : (it2 - 32);
            const char* src = (const char*)cp + (size_t)n2 * 131072
                              + (size_t)kc2 * 16384 + w * 1024 + l * 16;
            char* db = (char*)Blds[buf ^ 1] + w * 1024;
            #pragma unroll
            for (int i = 0; i < 4; ++i)
                __builtin_amdgcn_global_load_lds(
                    (const __attribute__((address_space(1))) unsigned int*)(src + i * 4096),
                    (__attribute__((address_space(3))) unsigned int*)(db + i * 4096),
                    16, 0, 0);
        }

        // compute current chunk
        {
            const char* Bl = (const char*)Blds[buf];
            f16x8 af[4], bfv[4];
            #pragma unroll
            for (int rt = 0; rt < 4; ++rt) {
                int row = rt * 16 + l15;
                int ab = (row * 512 + kc * 64 + lg * 16) ^ ((row & 7) << 4);
                af[rt] = *reinterpret_cast<const f16x8*>((const char*)Alds + ab);
            }
            #pragma unroll
            for (int ct = 0; ct < 4; ++ct) {
                int col = w * 64 + ct * 16 + l15;
                int bb = (col * 64 + lg * 16) ^ (((col >> 1) & 3) << 4);
                bfv[ct] = *reinterpret_cast<const f16x8*>(Bl + bb);
            }
            #pragma unroll
            for (int rt = 0; rt < 4; ++rt)
                #pragma unroll
                for (int ct = 0; ct < 4; ++ct)
                    acc[rt][ct] = __builtin_amdgcn_mfma_f32_16x16x32_f16(
                        af[rt], bfv[ct], acc[rt][ct], 0, 0, 0);
        }

        // epilogue at end of each 256-code iter
        if (kc == 7) {
            #pragma unroll
            for (int ct = 0; ct < 4; ++ct) {
                int j = n * 256 + w * 64 + ct * 16 + l15;
                float Sc = S_c[j];
                int app = 0;
                #pragma unroll
                for (int rt = 0; rt < 4; ++rt) {
                    #pragma unroll
                    for (int rg = 0; rg < 4; ++rg) {
                        int e = rt * 4 + rg;
                        float T = __fadd_rn(Szr[e], Sc);
                        // acc is dot * 2^14; -2*dot = -2^-13 * acc (exact scale)
                        float d = __builtin_fmaf(-0.0001220703125f, acc[rt][ct][rg], T);
                        if (d <= thr[e] + W) {
                            unsigned int pk =
                                ((unsigned int)(rt * 16 + lg * 4 + rg) << 13)
                                | (unsigned int)j;
                            int slot = atomicAdd(&qn[w], 1);
                            queue[w][slot & 255] = pk;
                            app = 1;
                        }
                        if (d < dmin[e]) dmin[e] = d;
                    }
                }
                if (__any(app)) {
                    int c0 = atomicAdd(&qn[w], 0);
                    while (c0 >= 64) {
                        unsigned int pk = queue[w][(c0 - 64 + l) & 255];
                        chain_check(pk, row0, z, cb, S_z, S_c, &best[pk >> 13]);
                        if (l == 0) atomicSub(&qn[w], 64);
                        c0 -= 64;
                    }
                }
            }
            // refresh prefix-min thresholds every 2 iters
            if ((it & 1) == 1) {
                #pragma unroll
                for (int e = 0; e < 16; ++e) {
                    float v = dmin[e];
                    v = fminf(v, __shfl_xor(v, 1));
                    v = fminf(v, __shfl_xor(v, 2));
                    v = fminf(v, __shfl_xor(v, 4));
                    v = fminf(v, __shfl_xor(v, 8));
                    thr[e] = v;
                }
            }
        }
        __syncthreads();
        buf ^= 1;
    }

    // drain remaining queue entries
    {
        int c0 = atomicAdd(&qn[w], 0);
        for (int b = 0; b < c0; b += 64) {
            if (l < c0 - b) {
                unsigned int pk = queue[w][(b + l) & 255];
                chain_check(pk, row0, z, cb, S_z, S_c, &best[pk >> 13]);
            }
        }
    }
    __syncthreads();
    if (t < 64) {
        unsigned int c = (unsigned int)(best[t] & 0xffffffffu);
        idx_out[row0 + t] = (int)c;
        idx_f32[row0 + t] = (float)c;
    }
}

// ---------------------------------------------------------------------------
// Kernel 2 (fallback, round-3 proven): fused fp32 GEMM + argmin.
// ---------------------------------------------------------------------------
__global__ __launch_bounds__(256) void k_argmin_fb(const float* __restrict__ z,
                                                   const float* __restrict__ cb,
                                                   const float* __restrict__ S_z,
                                                   const float* __restrict__ S_c,
                                                   int* __restrict__ idx_out,
                                                   float* __restrict__ idx_f32) {
    __shared__ float Zs[256 * 32];
    __shared__ float Cs[8 * 512];
    const int t    = threadIdx.x;
    const int tx   = t & 63;
    const int ty   = t >> 6;
    const int row0 = blockIdx.x * 32;
    for (int i = 0; i < 8; ++i) {
        int f  = i * 256 + t;
        int r  = f >> 6;
        int kq = f & 63;
        const float4 v = *reinterpret_cast<const float4*>(
            z + (size_t)(row0 + r) * E_DIM + kq * 4);
        int k = kq * 4;
        Zs[(k + 0) * 32 + r] = v.x;
        Zs[(k + 1) * 32 + r] = v.y;
        Zs[(k + 2) * 32 + r] = v.z;
        Zs[(k + 3) * 32 + r] = v.w;
    }
    float Szr[8];
    #pragma unroll
    for (int r = 0; r < 8; ++r) Szr[r] = S_z[row0 + ty * 8 + r];
    float dmin[8]; int imin[8];
    #pragma unroll
    for (int r = 0; r < 8; ++r) { dmin[r] = FLT_MAX; imin[r] = 0; }
    for (int n = 0; n < 16; ++n) {
        float acc[8][8];
        #pragma unroll
        for (int r = 0; r < 8; ++r)
            #pragma unroll
            for (int c = 0; c < 8; ++c) acc[r][c] = 0.0f;
        for (int kt = 0; kt < 32; ++kt) {
            __syncthreads();
            for (int i = 0; i < 4; ++i) {
                int f  = i * 256 + t;
                int c  = f >> 1;
                int kq = f & 1;
                const float4 v = *reinterpret_cast<const float4*>(
                    cb + (size_t)(n * 512 + c) * E_DIM + kt * 8 + kq * 4);
                int kl = kq * 4;
                Cs[(kl + 0) * 512 + c] = v.x;
                Cs[(kl + 1) * 512 + c] = v.y;
                Cs[(kl + 2) * 512 + c] = v.z;
                Cs[(kl + 3) * 512 + c] = v.w;
            }
            __syncthreads();
            #pragma unroll
            for (int kk = 0; kk < 8; ++kk) {
                const float4 a0 = *reinterpret_cast<const float4*>(&Zs[(kt * 8 + kk) * 32 + ty * 8]);
                const float4 a1 = *reinterpret_cast<const float4*>(&Zs[(kt * 8 + kk) * 32 + ty * 8 + 4]);
                const float4 bl = *reinterpret_cast<const float4*>(&Cs[kk * 512 + tx * 4]);
                const float4 bh = *reinterpret_cast<const float4*>(&Cs[kk * 512 + 256 + tx * 4]);
                const float ar[8] = {a0.x, a0.y, a0.z, a0.w, a1.x, a1.y, a1.z, a1.w};
                const float br[8] = {bl.x, bl.y, bl.z, bl.w, bh.x, bh.y, bh.z, bh.w};
                #pragma unroll
                for (int r = 0; r < 8; ++r)
                    #pragma unroll
                    for (int c = 0; c < 8; ++c)
                        acc[r][c] = __builtin_fmaf(ar[r], br[c], acc[r][c]);
            }
        }
        #pragma unroll
        for (int c = 0; c < 8; ++c) {
            int j = n * 512 + ((c < 4) ? (tx * 4 + c) : (256 + tx * 4 + (c - 4)));
            float scj = S_c[j];
            #pragma unroll
            for (int r = 0; r < 8; ++r) {
                float tt = __fadd_rn(Szr[r], scj);
                float d  = __builtin_fmaf(-2.0f, acc[r][c], tt);
                if (d < dmin[r]) { dmin[r] = d; imin[r] = j; }
            }
        }
    }
    __syncthreads();
    float* rd = Cs;
    int*   ri = reinterpret_cast<int*>(Cs) + 2048;
    #pragma unroll
    for (int r = 0; r < 8; ++r) {
        rd[(ty * 8 + r) * 64 + tx] = dmin[r];
        ri[(ty * 8 + r) * 64 + tx] = imin[r];
    }
    __syncthreads();
    if (t < 32) {
        float bestd = rd[t * 64]; int bi = ri[t * 64];
        for (int q = 1; q < 64; ++q) {
            float d  = rd[t * 64 + q];
            int   i2 = ri[t * 64 + q];
            if (d < bestd || (d == bestd && i2 < bi)) { bestd = d; bi = i2; }
        }
        idx_out[row0 + t] = bi;
        idx_f32[row0 + t] = (float)bi;
    }
}

// ---------------------------------------------------------------------------
// Kernel 3: gather + straight-through outputs + loss partials (f32 out).
// ---------------------------------------------------------------------------
__global__ __launch_bounds__(256) void k_outputs(const float* __restrict__ z,
                                                 const float* __restrict__ cb,
                                                 const int* __restrict__ idx,
                                                 float* __restrict__ out_zq,
                                                 float* __restrict__ out_res,
                                                 double* __restrict__ partials) {
    int b = blockIdx.x;
    int t = threadIdx.x;
    double acc = 0.0;
    for (int rr = 0; rr < 16; ++rr) {
        int row = b * 16 + rr;
        int id  = idx[row];
        int ids = id & (K_CODES - 1);
        float zq = cb[(size_t)ids * E_DIM + t];
        float zv = z[(size_t)row * E_DIM + t];
        float tmp  = __fsub_rn(zq, zv);
        float zqst = __fadd_rn(zv, tmp);
        float res  = __fsub_rn(zv, zqst);
        out_zq[(size_t)row * E_DIM + t]  = zqst;
        out_res[(size_t)row * E_DIM + t] = res;
        acc += (double)__fmul_rn(tmp, tmp);
    }
    __shared__ double sd[256];
    sd[t] = acc;
    __syncthreads();
    for (int s = 128; s > 0; s >>= 1) {
        if (t < s) sd[t] += sd[t + s];
        __syncthreads();
    }
    if (t == 0) partials[b] = sd[0];
}

__global__ __launch_bounds__(256) void k_loss(const double* __restrict__ partials,
                                              float* __restrict__ out_loss) {
    __shared__ double sd[256];
    int t = threadIdx.x;
    double a = 0.0;
    for (int i = 0; i < 8; ++i) a += partials[t * 8 + i];
    sd[t] = a;
    __syncthreads();
    for (int s = 128; s > 0; s >>= 1) {
        if (t < s) sd[t] += sd[t + s];
        __syncthreads();
    }
    if (t == 0) {
        float m = (float)(sd[0] / 8388608.0);
        out_loss[0] = __fadd_rn(m, __fmul_rn(1.0f, m));
    }
}

extern "C" void kernel_launch(void* const* d_in, const int* in_sizes, int n_in,
                              void* d_out, int out_size, void* d_ws, size_t ws_size,
                              hipStream_t stream) {
    const float* z  = (const float*)d_in[0];
    const float* cb = (const float*)d_in[1];
    float* out = (float*)d_out;

    char* ws = (char*)d_ws;
    float*  S_z      = (float*)(ws);
    float*  S_c      = (float*)(ws + 131072);
    int*    idx      = (int*)  (ws + 163840);
    double* partials = (double*)(ws + 294912);
    unsigned short* cp = (unsigned short*)(ws + 327680);

    float* out_zq   = out;
    float* out_idx  = out + 8388608;
    float* out_loss = out + 8421376;
    float* out_res  = out + 8421377;

    k_norms<<<1280, 256, 0, stream>>>(z, cb, S_z, S_c);
    if (ws_size >= (size_t)WS_NEED) {
        k_split    <<<512, 256, 0, stream>>>(cb, cp);
        k_prefilter<<<512, 256, 0, stream>>>(z, cb, cp, S_z, S_c, idx, out_idx);
    } else {
        k_argmin_fb<<<1024, 256, 0, stream>>>(z, cb, S_z, S_c, idx, out_idx);
    }
    k_outputs<<<2048, 256, 0, stream>>>(z, cb, idx, out_zq, out_res, partials);
    k_loss   <<<1,    256, 0, stream>>>(partials, out_loss);
}

// Round 5
// 390.840 us; speedup vs baseline: 4.6241x; 2.5260x over previous
//
#include <hip/hip_runtime.h>
#include <hip/hip_bf16.h>
#include <float.h>

// Problem constants
#define N_ROWS 32768   // B*L
#define E_DIM  256
#define K_CODES 8192

// d_out: FLOAT32, 16809985 elements: z_q_st[8388608] idx[32768] loss[1] res[8388608]
// ws layout (bytes):
//   S_z      f32[32768]   @ 0
//   S_c      f32[8192]    @ 131072
//   idx      i32[32768]   @ 163840
//   partials f64[2048]    @ 294912
//   c_packed u16[2097152] @ 327680   (4,194,304 B)  -> total 4,521,984
#define WS_NEED 4521984

typedef _Float16 f16x8 __attribute__((ext_vector_type(8)));
typedef float    f32x4 __attribute__((ext_vector_type(4)));

__device__ __forceinline__ float sqf(float x) { return __fmul_rn(x, x); }

// ---------------------------------------------------------------------------
// Kernel 1: row sum-of-squares, bit-exact numpy pairwise_sum emulation.
// ---------------------------------------------------------------------------
__global__ __launch_bounds__(256) void k_norms(const float* __restrict__ z,
                                               const float* __restrict__ cb,
                                               float* __restrict__ S_z,
                                               float* __restrict__ S_c) {
    __shared__ float tile[32][257];
    int b = blockIdx.x;
    const float* src; float* dst; int row0;
    if (b < 1024) { src = z;  dst = S_z; row0 = b * 32; }
    else          { src = cb; dst = S_c; row0 = (b - 1024) * 32; }
    int t = threadIdx.x;
    for (int i = 0; i < 8; ++i) {
        int f  = i * 256 + t;
        int r  = f >> 6;
        int c4 = f & 63;
        const float4 v = *reinterpret_cast<const float4*>(
            src + (size_t)(row0 + r) * E_DIM + c4 * 4);
        tile[r][c4 * 4 + 0] = v.x;
        tile[r][c4 * 4 + 1] = v.y;
        tile[r][c4 * 4 + 2] = v.z;
        tile[r][c4 * 4 + 3] = v.w;
    }
    __syncthreads();
    if (t < 32) {
        const float* a = tile[t];
        float halves[2];
        for (int h = 0; h < 2; ++h) {
            const float* p = a + h * 128;
            float r8[8];
            #pragma unroll
            for (int j = 0; j < 8; ++j) r8[j] = sqf(p[j]);
            for (int i = 8; i < 128; i += 8) {
                #pragma unroll
                for (int j = 0; j < 8; ++j) r8[j] = __fadd_rn(r8[j], sqf(p[i + j]));
            }
            halves[h] = __fadd_rn(
                __fadd_rn(__fadd_rn(r8[0], r8[1]), __fadd_rn(r8[2], r8[3])),
                __fadd_rn(__fadd_rn(r8[4], r8[5]), __fadd_rn(r8[6], r8[7])));
        }
        dst[row0 + t] = __fadd_rn(halves[0], halves[1]);
    }
}

// ---------------------------------------------------------------------------
// Kernel 1b: pack codebook fp16 (scaled 2^14) for per-lane fragment loads.
// Layout: [tile n = code>>8][kchunk kc = k>>5][g = (code&255)>>4]
//         [lane = (kin>>3)*16 + (code&15)][j = kin&7]  (16B per lane)
// -> one coalesced global_load_dwordx4 per (wave, ct) per chunk.
// ---------------------------------------------------------------------------
__global__ __launch_bounds__(256) void k_split(const float* __restrict__ cb,
                                               unsigned short* __restrict__ cp) {
    int e0 = (blockIdx.x * 256 + threadIdx.x) * 16;   // 512 blocks
    int code = e0 >> 8; int k0 = e0 & 255;
    int n = code >> 8; int col = code & 255;
    int g = col >> 4;  int l15c = col & 15;
    size_t base = (size_t)n * 131072 + (size_t)g * 1024;
    for (int i = 0; i < 4; ++i) {
        const float4 v = *reinterpret_cast<const float4*>(
            cb + (size_t)code * E_DIM + k0 + i * 4);
        float vv[4] = {v.x, v.y, v.z, v.w};
        #pragma unroll
        for (int q = 0; q < 4; ++q) {
            int k = k0 + i * 4 + q;
            _Float16 h = (_Float16)(__fmul_rn(vv[q], 16384.0f));
            int kc = k >> 5, kin = k & 31;
            int lane = (kin >> 3) * 16 + l15c;
            size_t byte = base + (size_t)kc * 16384 + lane * 16 + (kin & 7) * 2;
            *reinterpret_cast<unsigned short*>((char*)cp + byte)
                = __builtin_bit_cast(unsigned short, h);
        }
    }
}

// ---------------------------------------------------------------------------
// exact recheck chain: reference-order serial fp32 FMA dot, k ascending.
// ---------------------------------------------------------------------------
__device__ __forceinline__ void chain_check(unsigned int pk, int row0,
                                            const float* __restrict__ z,
                                            const float* __restrict__ cb,
                                            const float* __restrict__ S_z,
                                            const float* __restrict__ S_c,
                                            unsigned long long* best) {
    int r = pk >> 13;
    int c = pk & 8191;
    const float* zp = z + (size_t)(row0 + r) * E_DIM;
    const float* cp = cb + (size_t)c * E_DIM;
    float acc = 0.0f;
    #pragma unroll 8
    for (int k4 = 0; k4 < 64; ++k4) {
        const float4 a = *reinterpret_cast<const float4*>(zp + k4 * 4);
        const float4 b = *reinterpret_cast<const float4*>(cp + k4 * 4);
        acc = __builtin_fmaf(a.x, b.x, acc);
        acc = __builtin_fmaf(a.y, b.y, acc);
        acc = __builtin_fmaf(a.z, b.z, acc);
        acc = __builtin_fmaf(a.w, b.w, acc);
    }
    float T = __fadd_rn(S_z[row0 + r], S_c[c]);
    float d = __builtin_fmaf(-2.0f, acc, T);
    unsigned long long key = ((unsigned long long)__float_as_uint(d) << 32)
                             | (unsigned int)c;
    atomicMin(best, key);
}

// ---------------------------------------------------------------------------
// Kernel 2 (fast): fp16 MFMA prefilter + exact recheck argmin.
// 256 blocks x 512 thr (8 waves, 2 row-groups x 4 code-groups).
// BM=128 rows: A fp16 in LDS (64 KB, XOR-swizzled), staged once.
// B: NO LDS — per-lane coalesced global_load_dwordx4 into registers,
// double-buffered across chunks. ZERO barriers in the main loop.
// Per wave per chunk(32k): 4 B loads + 4 A ds_reads + 16 MFMA.
// ---------------------------------------------------------------------------
__global__ __launch_bounds__(512, 2) void k_prefilter(const float* __restrict__ z,
                                                      const float* __restrict__ cb,
                                                      const unsigned short* __restrict__ cp,
                                                      const float* __restrict__ S_z,
                                                      const float* __restrict__ S_c,
                                                      int* __restrict__ idx_out,
                                                      float* __restrict__ idx_f32) {
    __shared__ __align__(16) unsigned short Alds[32768];      // 64 KB
    __shared__ unsigned int  queue[8][256];                   // 8 KB
    __shared__ unsigned long long best[128];                  // 1 KB
    __shared__ int qn[8];

    const int t    = threadIdx.x;
    const int w    = t >> 6;
    const int l    = t & 63;
    const int l15  = l & 15;
    const int lg   = l >> 4;
    const int wr   = w >> 2;       // row half
    const int wc   = w & 3;        // code quarter
    const int row0 = blockIdx.x * 128;
    const float W = 3.0e-4f;

    if (t < 128) best[t] = ~0ull;
    if (t < 8)   qn[t] = 0;

    // ---- stage A: 128 rows x 256 k, fp32 -> fp16, XOR-swizzled ----
    for (int i = 0; i < 16; ++i) {
        int f  = i * 512 + t;          // 8192 float4
        int r  = f >> 6;               // [0,128)
        int c4 = f & 63;
        const float4 v = *reinterpret_cast<const float4*>(
            z + (size_t)(row0 + r) * E_DIM + c4 * 4);
        unsigned short h0 = __builtin_bit_cast(unsigned short, (_Float16)v.x);
        unsigned short h1 = __builtin_bit_cast(unsigned short, (_Float16)v.y);
        unsigned short h2 = __builtin_bit_cast(unsigned short, (_Float16)v.z);
        unsigned short h3 = __builtin_bit_cast(unsigned short, (_Float16)v.w);
        int byte = (r * 512 + c4 * 8) ^ ((r & 7) << 4);
        *reinterpret_cast<unsigned int*>((char*)Alds + byte)
            = (unsigned int)h0 | ((unsigned int)h1 << 16);
        *reinterpret_cast<unsigned int*>((char*)Alds + byte + 4)
            = (unsigned int)h2 | ((unsigned int)h3 << 16);
    }

    float Szr[16];
    #pragma unroll
    for (int rt = 0; rt < 4; ++rt)
        #pragma unroll
        for (int rg = 0; rg < 4; ++rg)
            Szr[rt * 4 + rg] = S_z[row0 + wr * 64 + rt * 16 + lg * 4 + rg];

    float dmin[16], thr[16];
    #pragma unroll
    for (int e = 0; e < 16; ++e) { dmin[e] = FLT_MAX; thr[e] = -FLT_MAX; }

    __syncthreads();   // A ready; no more barriers until the end

    f32x4 acc[4][4];

    // B address helper data
    const char* cpb = (const char*)cp + (size_t)(wc * 4) * 1024 + (size_t)l * 16;

    f16x8 bA[4], bB[4];
    // preload ci = 0 (n=0, kc=0)
    #pragma unroll
    for (int ct = 0; ct < 4; ++ct)
        bA[ct] = *reinterpret_cast<const f16x8*>(cpb + ct * 1024);

    // epilogue lambda: runs at kc==7 for code-tile n
    auto epilogue = [&](int n, int it) {
        #pragma unroll
        for (int ct = 0; ct < 4; ++ct) {
            int j = n * 256 + wc * 64 + ct * 16 + l15;
            float Sc = S_c[j];
            int app = 0;
            #pragma unroll
            for (int rt = 0; rt < 4; ++rt) {
                #pragma unroll
                for (int rg = 0; rg < 4; ++rg) {
                    int e = rt * 4 + rg;
                    float T = __fadd_rn(Szr[e], Sc);
                    float d = __builtin_fmaf(-0.0001220703125f, acc[rt][ct][rg], T);
                    if (d <= thr[e] + W) {
                        unsigned int pk =
                            ((unsigned int)(wr * 64 + rt * 16 + lg * 4 + rg) << 13)
                            | (unsigned int)j;
                        int slot = atomicAdd(&qn[w], 1);
                        queue[w][slot & 255] = pk;
                        app = 1;
                    }
                    if (d < dmin[e]) dmin[e] = d;
                }
            }
            if (__any(app)) {
                int c0 = atomicAdd(&qn[w], 0);
                while (c0 >= 64) {
                    unsigned int pk = queue[w][(c0 - 64 + l) & 255];
                    chain_check(pk, row0, z, cb, S_z, S_c, &best[pk >> 13]);
                    if (l == 0) atomicSub(&qn[w], 64);
                    c0 -= 64;
                }
            }
        }
        if ((it & 1) == 1) {
            #pragma unroll
            for (int e = 0; e < 16; ++e) {
                float v = dmin[e];
                v = fminf(v, __shfl_xor(v, 1));
                v = fminf(v, __shfl_xor(v, 2));
                v = fminf(v, __shfl_xor(v, 4));
                v = fminf(v, __shfl_xor(v, 8));
                thr[e] = v;
            }
        }
    };

    // one pipeline step: compute chunk ci from `cur`, prefetch ci+1 into `nxt`
    auto step = [&](int ci, f16x8 (&cur)[4], f16x8 (&nxt)[4]) {
        const int kc = ci & 7;
        const int it = ci >> 3;
        const int n  = (it < 32) ? it : (it - 32);

        if (kc == 0) {
            #pragma unroll
            for (int rt = 0; rt < 4; ++rt)
                #pragma unroll
                for (int ct = 0; ct < 4; ++ct)
                    acc[rt][ct] = (f32x4){0.f, 0.f, 0.f, 0.f};
        }

        // prefetch next chunk into nxt (last step reloads current; harmless)
        {
            int cj  = (ci + 1 < 272) ? (ci + 1) : ci;
            int kc2 = cj & 7, it2 = cj >> 3;
            int n2  = (it2 < 32) ? it2 : (it2 - 32);
            const char* src = cpb + (size_t)n2 * 131072 + (size_t)kc2 * 16384;
            #pragma unroll
            for (int ct = 0; ct < 4; ++ct)
                nxt[ct] = *reinterpret_cast<const f16x8*>(src + ct * 1024);
        }

        // A fragments + 16 MFMA
        {
            f16x8 af[4];
            #pragma unroll
            for (int rt = 0; rt < 4; ++rt) {
                int row = wr * 64 + rt * 16 + l15;
                int ab  = (row * 512 + kc * 64 + lg * 16) ^ ((row & 7) << 4);
                af[rt] = *reinterpret_cast<const f16x8*>((const char*)Alds + ab);
            }
            #pragma unroll
            for (int rt = 0; rt < 4; ++rt)
                #pragma unroll
                for (int ct = 0; ct < 4; ++ct)
                    acc[rt][ct] = __builtin_amdgcn_mfma_f32_16x16x32_f16(
                        af[rt], cur[ct], acc[rt][ct], 0, 0, 0);
        }

        if (kc == 7) epilogue(n, it);
    };

    for (int h = 0; h < 136; ++h) {     // 272 chunks: 34 code-tiles x 8
        step(2 * h,     bA, bB);
        step(2 * h + 1, bB, bA);
    }

    // drain remaining queue entries (per-wave, no barrier needed)
    {
        int c0 = atomicAdd(&qn[w], 0);
        for (int b = 0; b < c0; b += 64) {
            if (l < c0 - b) {
                unsigned int pk = queue[w][(b + l) & 255];
                chain_check(pk, row0, z, cb, S_z, S_c, &best[pk >> 13]);
            }
        }
    }
    __syncthreads();
    if (t < 128) {
        unsigned int c = (unsigned int)(best[t] & 0xffffffffu);
        idx_out[row0 + t] = (int)c;
        idx_f32[row0 + t] = (float)c;
    }
}

// ---------------------------------------------------------------------------
// Kernel 2 (fallback, round-3 proven): fused fp32 GEMM + argmin.
// ---------------------------------------------------------------------------
__global__ __launch_bounds__(256) void k_argmin_fb(const float* __restrict__ z,
                                                   const float* __restrict__ cb,
                                                   const float* __restrict__ S_z,
                                                   const float* __restrict__ S_c,
                                                   int* __restrict__ idx_out,
                                                   float* __restrict__ idx_f32) {
    __shared__ float Zs[256 * 32];
    __shared__ float Cs[8 * 512];
    const int t    = threadIdx.x;
    const int tx   = t & 63;
    const int ty   = t >> 6;
    const int row0 = blockIdx.x * 32;
    for (int i = 0; i < 8; ++i) {
        int f  = i * 256 + t;
        int r  = f >> 6;
        int kq = f & 63;
        const float4 v = *reinterpret_cast<const float4*>(
            z + (size_t)(row0 + r) * E_DIM + kq * 4);
        int k = kq * 4;
        Zs[(k + 0) * 32 + r] = v.x;
        Zs[(k + 1) * 32 + r] = v.y;
        Zs[(k + 2) * 32 + r] = v.z;
        Zs[(k + 3) * 32 + r] = v.w;
    }
    float Szr[8];
    #pragma unroll
    for (int r = 0; r < 8; ++r) Szr[r] = S_z[row0 + ty * 8 + r];
    float dmin[8]; int imin[8];
    #pragma unroll
    for (int r = 0; r < 8; ++r) { dmin[r] = FLT_MAX; imin[r] = 0; }
    for (int n = 0; n < 16; ++n) {
        float acc[8][8];
        #pragma unroll
        for (int r = 0; r < 8; ++r)
            #pragma unroll
            for (int c = 0; c < 8; ++c) acc[r][c] = 0.0f;
        for (int kt = 0; kt < 32; ++kt) {
            __syncthreads();
            for (int i = 0; i < 4; ++i) {
                int f  = i * 256 + t;
                int c  = f >> 1;
                int kq = f & 1;
                const float4 v = *reinterpret_cast<const float4*>(
                    cb + (size_t)(n * 512 + c) * E_DIM + kt * 8 + kq * 4);
                int kl = kq * 4;
                Cs[(kl + 0) * 512 + c] = v.x;
                Cs[(kl + 1) * 512 + c] = v.y;
                Cs[(kl + 2) * 512 + c] = v.z;
                Cs[(kl + 3) * 512 + c] = v.w;
            }
            __syncthreads();
            #pragma unroll
            for (int kk = 0; kk < 8; ++kk) {
                const float4 a0 = *reinterpret_cast<const float4*>(&Zs[(kt * 8 + kk) * 32 + ty * 8]);
                const float4 a1 = *reinterpret_cast<const float4*>(&Zs[(kt * 8 + kk) * 32 + ty * 8 + 4]);
                const float4 bl = *reinterpret_cast<const float4*>(&Cs[kk * 512 + tx * 4]);
                const float4 bh = *reinterpret_cast<const float4*>(&Cs[kk * 512 + 256 + tx * 4]);
                const float ar[8] = {a0.x, a0.y, a0.z, a0.w, a1.x, a1.y, a1.z, a1.w};
                const float br[8] = {bl.x, bl.y, bl.z, bl.w, bh.x, bh.y, bh.z, bh.w};
                #pragma unroll
                for (int r = 0; r < 8; ++r)
                    #pragma unroll
                    for (int c = 0; c < 8; ++c)
                        acc[r][c] = __builtin_fmaf(ar[r], br[c], acc[r][c]);
            }
        }
        #pragma unroll
        for (int c = 0; c < 8; ++c) {
            int j = n * 512 + ((c < 4) ? (tx * 4 + c) : (256 + tx * 4 + (c - 4)));
            float scj = S_c[j];
            #pragma unroll
            for (int r = 0; r < 8; ++r) {
                float tt = __fadd_rn(Szr[r], scj);
                float d  = __builtin_fmaf(-2.0f, acc[r][c], tt);
                if (d < dmin[r]) { dmin[r] = d; imin[r] = j; }
            }
        }
    }
    __syncthreads();
    float* rd = Cs;
    int*   ri = reinterpret_cast<int*>(Cs) + 2048;
    #pragma unroll
    for (int r = 0; r < 8; ++r) {
        rd[(ty * 8 + r) * 64 + tx] = dmin[r];
        ri[(ty * 8 + r) * 64 + tx] = imin[r];
    }
    __syncthreads();
    if (t < 32) {
        float bestd = rd[t * 64]; int bi = ri[t * 64];
        for (int q = 1; q < 64; ++q) {
            float d  = rd[t * 64 + q];
            int   i2 = ri[t * 64 + q];
            if (d < bestd || (d == bestd && i2 < bi)) { bestd = d; bi = i2; }
        }
        idx_out[row0 + t] = bi;
        idx_f32[row0 + t] = (float)bi;
    }
}

// ---------------------------------------------------------------------------
// Kernel 3: gather + straight-through outputs + loss partials (f32 out).
// ---------------------------------------------------------------------------
__global__ __launch_bounds__(256) void k_outputs(const float* __restrict__ z,
                                                 const float* __restrict__ cb,
                                                 const int* __restrict__ idx,
                                                 float* __restrict__ out_zq,
                                                 float* __restrict__ out_res,
                                                 double* __restrict__ partials) {
    int b = blockIdx.x;
    int t = threadIdx.x;
    double acc = 0.0;
    for (int rr = 0; rr < 16; ++rr) {
        int row = b * 16 + rr;
        int id  = idx[row];
        int ids = id & (K_CODES - 1);
        float zq = cb[(size_t)ids * E_DIM + t];
        float zv = z[(size_t)row * E_DIM + t];
        float tmp  = __fsub_rn(zq, zv);
        float zqst = __fadd_rn(zv, tmp);
        float res  = __fsub_rn(zv, zqst);
        out_zq[(size_t)row * E_DIM + t]  = zqst;
        out_res[(size_t)row * E_DIM + t] = res;
        acc += (double)__fmul_rn(tmp, tmp);
    }
    __shared__ double sd[256];
    sd[t] = acc;
    __syncthreads();
    for (int s = 128; s > 0; s >>= 1) {
        if (t < s) sd[t] += sd[t + s];
        __syncthreads();
    }
    if (t == 0) partials[b] = sd[0];
}

__global__ __launch_bounds__(256) void k_loss(const double* __restrict__ partials,
                                              float* __restrict__ out_loss) {
    __shared__ double sd[256];
    int t = threadIdx.x;
    double a = 0.0;
    for (int i = 0; i < 8; ++i) a += partials[t * 8 + i];
    sd[t] = a;
    __syncthreads();
    for (int s = 128; s > 0; s >>= 1) {
        if (t < s) sd[t] += sd[t + s];
        __syncthreads();
    }
    if (t == 0) {
        float m = (float)(sd[0] / 8388608.0);
        out_loss[0] = __fadd_rn(m, __fmul_rn(1.0f, m));
    }
}

extern "C" void kernel_launch(void* const* d_in, const int* in_sizes, int n_in,
                              void* d_out, int out_size, void* d_ws, size_t ws_size,
                              hipStream_t stream) {
    const float* z  = (const float*)d_in[0];
    const float* cb = (const float*)d_in[1];
    float* out = (float*)d_out;

    char* ws = (char*)d_ws;
    float*  S_z      = (float*)(ws);
    float*  S_c      = (float*)(ws + 131072);
    int*    idx      = (int*)  (ws + 163840);
    double* partials = (double*)(ws + 294912);
    unsigned short* cp = (unsigned short*)(ws + 327680);

    float* out_zq   = out;
    float* out_idx  = out + 8388608;
    float* out_loss = out + 8421376;
    float* out_res  = out + 8421377;

    k_norms<<<1280, 256, 0, stream>>>(z, cb, S_z, S_c);
    if (ws_size >= (size_t)WS_NEED) {
        k_split    <<<512, 256, 0, stream>>>(cb, cp);
        k_prefilter<<<256, 512, 0, stream>>>(z, cb, cp, S_z, S_c, idx, out_idx);
    } else {
        k_argmin_fb<<<1024, 256, 0, stream>>>(z, cb, S_z, S_c, idx, out_idx);
    }
    k_outputs<<<2048, 256, 0, stream>>>(z, cb, idx, out_zq, out_res, partials);
    k_loss   <<<1,    256, 0, stream>>>(partials, out_loss);
}